// Round 1
// baseline (646.506 us; speedup 1.0000x reference)
//
#include <hip/hip_runtime.h>
#include <hip/hip_bf16.h>
#include <stdint.h>

#define B_   2
#define N_   2048
#define H_   16
#define DQK_ 128
#define DV_  128
#define E_   2048
#define CH_  64
#define NC_  32
#define M_   (B_*N_)   // 4096

using bf16x8 = __attribute__((ext_vector_type(8))) __bf16;
using f32x4  = __attribute__((ext_vector_type(4))) float;
typedef __hip_bfloat16 bf16_t;

// async global->LDS, 16B per lane. LDS dest must be wave-uniform base; each
// lane supplies its own global address. Integer round-trip for addrspace casts
// (low 32 bits of a flat LDS pointer == LDS byte offset).
__device__ __forceinline__ void gload_lds16(const void* g, void* l) {
  __builtin_amdgcn_global_load_lds(
      (const __attribute__((address_space(1))) void*)(uintptr_t)g,
      (__attribute__((address_space(3))) void*)(uint32_t)(uintptr_t)l,
      16, 0, 0);
}

// ---------------- f32 -> bf16 convert ----------------
__global__ void cvt_bf16_kernel(const float* __restrict__ src,
                                bf16_t* __restrict__ dst, int n4) {
  int i = blockIdx.x * 256 + threadIdx.x;
  if (i >= n4) return;
  float4 v = ((const float4*)src)[i];
  bf16_t o0 = __float2bfloat16(v.x), o1 = __float2bfloat16(v.y);
  bf16_t o2 = __float2bfloat16(v.z), o3 = __float2bfloat16(v.w);
  ushort4 p;
  p.x = *(unsigned short*)&o0; p.y = *(unsigned short*)&o1;
  p.z = *(unsigned short*)&o2; p.w = *(unsigned short*)&o3;
  ((ushort4*)dst)[i] = p;
}

// ---------------- GEMM: C[M,N] = A[M,K] @ Bw[N,K]^T + bias ----------------
// m97 structure: 128x128 tile, BK=32, 4 waves (2x2), 4x4 16x16x32 frags/wave.
template<bool OUT_BF16>
__global__ __launch_bounds__(256)
void gemm_kernel(const bf16_t* __restrict__ A, const bf16_t* __restrict__ Bw,
                 const float* __restrict__ bias, void* __restrict__ Cout,
                 int M, int N, int K) {
  __shared__ alignas(16) bf16_t As[128*32];
  __shared__ alignas(16) bf16_t Bs[128*32];
  const int tid = threadIdx.x;
  const int wave = tid >> 6, lane = tid & 63;
  const int wr = wave >> 1, wc = wave & 1;
  const int l16 = lane & 15, lhi = lane >> 4;
  const int row0 = blockIdx.y * 128, col0 = blockIdx.x * 128;
  const int srow = tid >> 2;          // 0..63
  const int skoff = (tid & 3) * 8;    // bf16 elems

  f32x4 acc[4][4] = {};

  for (int k0 = 0; k0 < K; k0 += 32) {
    __syncthreads();
    gload_lds16(A  + (size_t)(row0 +      srow)*K + k0 + skoff, (char*)As +        wave*1024);
    gload_lds16(A  + (size_t)(row0 + 64 + srow)*K + k0 + skoff, (char*)As + 4096 + wave*1024);
    gload_lds16(Bw + (size_t)(col0 +      srow)*K + k0 + skoff, (char*)Bs +        wave*1024);
    gload_lds16(Bw + (size_t)(col0 + 64 + srow)*K + k0 + skoff, (char*)Bs + 4096 + wave*1024);
    __syncthreads();
    bf16x8 a[4], b[4];
#pragma unroll
    for (int m = 0; m < 4; m++)
      a[m] = *(const bf16x8*)((const char*)As + ((wr*64 + m*16 + l16)*32 + lhi*8)*2);
#pragma unroll
    for (int n = 0; n < 4; n++)
      b[n] = *(const bf16x8*)((const char*)Bs + ((wc*64 + n*16 + l16)*32 + lhi*8)*2);
#pragma unroll
    for (int m = 0; m < 4; m++)
#pragma unroll
      for (int n = 0; n < 4; n++)
        acc[m][n] = __builtin_amdgcn_mfma_f32_16x16x32_bf16(a[m], b[n], acc[m][n], 0, 0, 0);
  }

#pragma unroll
  for (int n = 0; n < 4; n++) {
    const int col = col0 + wc*64 + n*16 + l16;
    const float bv = bias[col];
#pragma unroll
    for (int m = 0; m < 4; m++) {
      const int rbase = row0 + wr*64 + m*16 + lhi*4;
#pragma unroll
      for (int j = 0; j < 4; j++) {
        float v = acc[m][n][j] + bv;
        if (OUT_BF16) ((bf16_t*)Cout)[(size_t)(rbase + j)*N + col] = __float2bfloat16(v);
        else          ((float*)Cout)[(size_t)(rbase + j)*N + col] = v;
      }
    }
  }
}

// ---------------- rotary (xPos) on q,k in-place; k scaled 1/sqrt(dqk) -------
__global__ void rotary_kernel(bf16_t* __restrict__ q, bf16_t* __restrict__ k,
                              const int* __restrict__ startp) {
  int t = blockIdx.x * 256 + threadIdx.x;     // B*N*H*16 groups of 8 elems
  if (t >= B_*N_*H_*16) return;
  int dg = t & 15;
  int rest = t >> 4;                          // (b*N+n)*H + h
  int n = (rest >> 4) & (N_ - 1);
  float pos = (float)(startp[0] + n);
  size_t base = (size_t)rest * 128 + dg * 8;
  bf16x8 qv = *(const bf16x8*)(q + base);
  bf16x8 kv = *(const bf16x8*)(k + base);
  bf16x8 qo, ko;
  const float KS = 0.08838834764831843f;      // 1/sqrt(128)
#pragma unroll
  for (int p = 0; p < 4; p++) {
    int j = dg * 4 + p;                       // pair index 0..63
    float theta = exp2f(-13.287712379549449f * ((float)j * (1.0f/63.0f)));
    float ang = pos * theta;
    float s, c;
    sincosf(ang, &s, &c);
    float qa = (float)qv[2*p], qb = (float)qv[2*p+1];
    float ka = (float)kv[2*p], kb = (float)kv[2*p+1];
    qo[2*p]   = (__bf16)(qa*c - qb*s);
    qo[2*p+1] = (__bf16)(qb*c + qa*s);
    ko[2*p]   = (__bf16)((ka*c - kb*s) * KS);
    ko[2*p+1] = (__bf16)((kb*c + ka*s) * KS);
  }
  *(bf16x8*)(q + base) = qo;
  *(bf16x8*)(k + base) = ko;
}

// ---------------- chunked retention scan ----------------
// One workgroup per (b,h). S^T kept in f32 regs (C/D layout), bf16 copy in LDS
// for the q.S B-operand. All LDS rows XOR-swizzled: byte ^= (row&7)<<4.
__global__ __launch_bounds__(256)
void scan_kernel(const bf16_t* __restrict__ qb, const bf16_t* __restrict__ kb,
                 const bf16_t* __restrict__ vb, const float* __restrict__ prev,
                 float* __restrict__ o_pre, float* __restrict__ out_state) {
  __shared__ alignas(16) char lds[65536];
  char* S_bf = lds;            // 32K: S^T bf16 [e:128][d:128], swizzled
  char* vts  = lds + 32768;    // 16K: V^T bf16 [e:128][j:64], swizzled
  char* kts  = lds + 49152;    // 16K: K'^T [d:128][j:64] / att [i:64][j:64]

  const int tid = threadIdx.x, wave = tid >> 6, lane = tid & 63;
  const int l16 = lane & 15, lhi = lane >> 4;
  const int bh = blockIdx.x;                  // b*H + h
  const int h = bh & (H_ - 1);
  const float log2g = (float)(log2(1.0 - exp2((double)(-5 - h))));
  const float cdecay = exp2f(64.0f * log2g);

  const size_t rowstride = (size_t)H_ * 128;
  const size_t bhbase = (size_t)(bh >> 4) * N_ * rowstride + (size_t)h * 128;

  // ---- load prev_state into S regs (row=e, col=d per C/D layout) ----
  f32x4 S[2][8];
#pragma unroll
  for (int et = 0; et < 2; et++)
#pragma unroll
    for (int dt = 0; dt < 8; dt++)
#pragma unroll
      for (int j = 0; j < 4; j++) {
        int e = (2*wave + et)*16 + lhi*4 + j;
        int d = dt*16 + l16;
        S[et][dt][j] = prev[((size_t)bh*128 + d)*128 + e];
      }

  auto writeSbf = [&]() {
#pragma unroll
    for (int et = 0; et < 2; et++)
#pragma unroll
      for (int dt = 0; dt < 8; dt++)
#pragma unroll
        for (int j = 0; j < 4; j++) {
          int e = (2*wave + et)*16 + lhi*4 + j;
          int d = dt*16 + l16;
          *(__bf16*)(S_bf + e*256 + ((d*2) ^ ((e&7)<<4))) = (__bf16)S[et][dt][j];
        }
  };
  writeSbf();
  __syncthreads();

  for (int ch = 0; ch < NC_; ch++) {
    const int n0 = ch * 64;
    // ---- q fragments (A-operand, rows i = wave*16 + l16) ----
    bf16x8 qf[4];
#pragma unroll
    for (int dk = 0; dk < 4; dk++)
      qf[dk] = *(const bf16x8*)(qb + bhbase + (size_t)(n0 + wave*16 + l16)*rowstride + dk*32 + lhi*8);

    // ---- oacc = q @ S_old (B-operand from S_bf), then cross_decay scale ----
    f32x4 oacc[8] = {};
#pragma unroll
    for (int et = 0; et < 8; et++) {
#pragma unroll
      for (int dk = 0; dk < 4; dk++) {
        int e = et*16 + l16;
        bf16x8 sf = *(const bf16x8*)(S_bf + e*256 + (((dk*32 + lhi*8)*2) ^ ((e&7)<<4)));
        oacc[et] = __builtin_amdgcn_mfma_f32_16x16x32_bf16(qf[dk], sf, oacc[et], 0, 0, 0);
      }
    }
#pragma unroll
    for (int j = 0; j < 4; j++) {
      int i = wave*16 + lhi*4 + j;
      float f = exp2f((float)(i + 1) * log2g);
#pragma unroll
      for (int et = 0; et < 8; et++) oacc[et][j] *= f;
    }

    // ---- att = (q k^T) * Dmat (k B-frags straight from global) ----
    f32x4 aacc[4] = {};
#pragma unroll
    for (int jt = 0; jt < 4; jt++) {
#pragma unroll
      for (int dk = 0; dk < 4; dk++) {
        bf16x8 kf = *(const bf16x8*)(kb + bhbase + (size_t)(n0 + jt*16 + l16)*rowstride + dk*32 + lhi*8);
        aacc[jt] = __builtin_amdgcn_mfma_f32_16x16x32_bf16(qf[dk], kf, aacc[jt], 0, 0, 0);
      }
    }
#pragma unroll
    for (int jt = 0; jt < 4; jt++)
#pragma unroll
      for (int j = 0; j < 4; j++) {
        int i = wave*16 + lhi*4 + j;
        int jc = jt*16 + l16;
        aacc[jt][j] *= (i >= jc) ? exp2f((float)(i - jc) * log2g) : 0.0f;
      }

    __syncthreads();  // S_bf reads + prev-chunk vts/att reads complete

    // ---- build K'^T (kv_decay folded) and V^T in LDS; decay S regs ----
#pragma unroll
    for (int it = 0; it < 4; it++) {
      int j = it*16 + (tid >> 4);
      int e0 = (tid & 15) * 8;
      bf16x8 vv = *(const bf16x8*)(vb + bhbase + (size_t)(n0 + j)*rowstride + e0);
      bf16x8 kk = *(const bf16x8*)(kb + bhbase + (size_t)(n0 + j)*rowstride + e0);
      float kvd = exp2f((float)(63 - j) * log2g);
#pragma unroll
      for (int m = 0; m < 8; m++) {
        int e = e0 + m;
        *(__bf16*)(vts + e*128 + ((j*2) ^ ((e&7)<<4))) = vv[m];
        *(__bf16*)(kts + e*128 + ((j*2) ^ ((e&7)<<4))) = (__bf16)((float)kk[m] * kvd);
      }
    }
#pragma unroll
    for (int et = 0; et < 2; et++)
#pragma unroll
      for (int dt = 0; dt < 8; dt++)
#pragma unroll
        for (int j = 0; j < 4; j++) S[et][dt][j] *= cdecay;
    __syncthreads();

    // ---- S += V^T . K'  (A = V^T rows e, B = K'^T rows d) ----
#pragma unroll
    for (int et = 0; et < 2; et++) {
#pragma unroll
      for (int kk2 = 0; kk2 < 2; kk2++) {
        int e = (2*wave + et)*16 + l16;
        bf16x8 vf = *(const bf16x8*)(vts + e*128 + (((kk2*32 + lhi*8)*2) ^ ((e&7)<<4)));
#pragma unroll
        for (int dt = 0; dt < 8; dt++) {
          int d = dt*16 + l16;
          bf16x8 kf = *(const bf16x8*)(kts + d*128 + (((kk2*32 + lhi*8)*2) ^ ((d&7)<<4)));
          S[et][dt] = __builtin_amdgcn_mfma_f32_16x16x32_bf16(vf, kf, S[et][dt], 0, 0, 0);
        }
      }
    }
    writeSbf();       // new S_bf for next chunk (different buffer than kts/vts)
    __syncthreads();  // kts fully consumed -> reuse as att_s

    // ---- att -> LDS (bf16, swizzled) ----
#pragma unroll
    for (int jt = 0; jt < 4; jt++)
#pragma unroll
      for (int j = 0; j < 4; j++) {
        int i = wave*16 + lhi*4 + j;
        int jc = jt*16 + l16;
        *(__bf16*)(kts + i*128 + ((jc*2) ^ ((i&7)<<4))) = (__bf16)aacc[jt][j];
      }
    __syncthreads();

    // ---- oacc += att @ V ----
#pragma unroll
    for (int kk2 = 0; kk2 < 2; kk2++) {
      int i = wave*16 + l16;
      bf16x8 af = *(const bf16x8*)(kts + i*128 + (((kk2*32 + lhi*8)*2) ^ ((i&7)<<4)));
#pragma unroll
      for (int et = 0; et < 8; et++) {
        int e = et*16 + l16;
        bf16x8 vf = *(const bf16x8*)(vts + e*128 + (((kk2*32 + lhi*8)*2) ^ ((e&7)<<4)));
        oacc[et] = __builtin_amdgcn_mfma_f32_16x16x32_bf16(af, vf, oacc[et], 0, 0, 0);
      }
    }

    // ---- store o (pre-groupnorm, f32) ----
#pragma unroll
    for (int et = 0; et < 8; et++)
#pragma unroll
      for (int j = 0; j < 4; j++) {
        int i = wave*16 + lhi*4 + j;
        o_pre[bhbase + (size_t)(n0 + i)*rowstride + et*16 + l16] = oacc[et][j];
      }
  }

  // ---- final state (B,H,DQK,DV): out[d][e] = S^T regs ----
#pragma unroll
  for (int et = 0; et < 2; et++)
#pragma unroll
    for (int dt = 0; dt < 8; dt++)
#pragma unroll
      for (int j = 0; j < 4; j++) {
        int e = (2*wave + et)*16 + lhi*4 + j;
        int d = dt*16 + l16;
        out_state[((size_t)bh*128 + d)*128 + e] = S[et][dt][j];
      }
}

// ---------------- GroupNorm(per head, no affine) * SiLU(gate) ----------------
__global__ __launch_bounds__(256)
void gn_gate_kernel(const float* __restrict__ o_pre, const bf16_t* __restrict__ gbuf,
                    bf16_t* __restrict__ gated) {
  int row = blockIdx.x * 4 + (threadIdx.x >> 6);   // (b*N+n)*H + h
  int lane = threadIdx.x & 63;
  size_t base = (size_t)row * 128 + lane * 2;
  float2 xv = *(const float2*)(o_pre + base);
  float s = xv.x + xv.y, ss = xv.x*xv.x + xv.y*xv.y;
#pragma unroll
  for (int off = 1; off < 64; off <<= 1) {
    s  += __shfl_xor(s, off);
    ss += __shfl_xor(ss, off);
  }
  float mu  = s * (1.0f/128.0f);
  float inv = rsqrtf(ss * (1.0f/128.0f) - mu*mu + 1e-6f);
  float g0 = __bfloat162float(gbuf[base]),  g1 = __bfloat162float(gbuf[base+1]);
  float r0 = (xv.x - mu) * inv * (g0 / (1.0f + expf(-g0)));
  float r1 = (xv.y - mu) * inv * (g1 / (1.0f + expf(-g1)));
  gated[base]   = __float2bfloat16(r0);
  gated[base+1] = __float2bfloat16(r1);
}

// ---------------- launch ----------------
extern "C" void kernel_launch(void* const* d_in, const int* in_sizes, int n_in,
                              void* d_out, int out_size, void* d_ws, size_t ws_size,
                              hipStream_t stream) {
  const float* x    = (const float*)d_in[0];
  const float* prev = (const float*)d_in[1];
  const float* Wq = (const float*)d_in[2];  const float* bq = (const float*)d_in[3];
  const float* Wk = (const float*)d_in[4];  const float* bk = (const float*)d_in[5];
  const float* Wv = (const float*)d_in[6];  const float* bv = (const float*)d_in[7];
  const float* Wg = (const float*)d_in[8];  const float* bg = (const float*)d_in[9];
  const float* Wo = (const float*)d_in[10]; const float* bo = (const float*)d_in[11];
  const int* startp = (const int*)d_in[12];

  float* out = (float*)d_out;                               // B*N*E
  float* out_state = out + (size_t)B_*N_*E_;                // B*H*DQK*DV

  char* w = (char*)d_ws;
  const size_t XN = (size_t)B_*N_*E_;       // 8388608 elems
  const size_t WN = (size_t)E_*E_;          // 4194304 elems
  bf16_t* xb   = (bf16_t*)w;             w += XN*2;   // also reused as `gated`
  bf16_t* qbuf = (bf16_t*)w;             w += XN*2;
  bf16_t* kbuf = (bf16_t*)w;             w += XN*2;
  bf16_t* vbuf = (bf16_t*)w;             w += XN*2;
  bf16_t* gbuf = (bf16_t*)w;             w += XN*2;
  bf16_t* wqb  = (bf16_t*)w;             w += WN*2;
  bf16_t* wkb  = (bf16_t*)w;             w += WN*2;
  bf16_t* wvb  = (bf16_t*)w;             w += WN*2;
  bf16_t* wgb  = (bf16_t*)w;             w += WN*2;
  bf16_t* wob  = (bf16_t*)w;             w += WN*2;
  float*  o_pre = (float*)w;             w += XN*4;

  // converts
  cvt_bf16_kernel<<<(int)(XN/4/256), 256, 0, stream>>>(x,  xb,  (int)(XN/4));
  cvt_bf16_kernel<<<(int)(WN/4/256), 256, 0, stream>>>(Wq, wqb, (int)(WN/4));
  cvt_bf16_kernel<<<(int)(WN/4/256), 256, 0, stream>>>(Wk, wkb, (int)(WN/4));
  cvt_bf16_kernel<<<(int)(WN/4/256), 256, 0, stream>>>(Wv, wvb, (int)(WN/4));
  cvt_bf16_kernel<<<(int)(WN/4/256), 256, 0, stream>>>(Wg, wgb, (int)(WN/4));
  cvt_bf16_kernel<<<(int)(WN/4/256), 256, 0, stream>>>(Wo, wob, (int)(WN/4));

  dim3 gg(E_/128, M_/128);  // (16, 32)
  gemm_kernel<true><<<gg, 256, 0, stream>>>(xb, wqb, bq, (void*)qbuf, M_, E_, E_);
  gemm_kernel<true><<<gg, 256, 0, stream>>>(xb, wkb, bk, (void*)kbuf, M_, E_, E_);
  gemm_kernel<true><<<gg, 256, 0, stream>>>(xb, wvb, bv, (void*)vbuf, M_, E_, E_);
  gemm_kernel<true><<<gg, 256, 0, stream>>>(xb, wgb, bg, (void*)gbuf, M_, E_, E_);

  rotary_kernel<<<(B_*N_*H_*16)/256, 256, 0, stream>>>(qbuf, kbuf, startp);

  scan_kernel<<<B_*H_, 256, 0, stream>>>(qbuf, kbuf, vbuf, prev, o_pre, out_state);

  gn_gate_kernel<<<(B_*N_*H_)/4, 256, 0, stream>>>(o_pre, gbuf, xb /*gated*/);

  gemm_kernel<false><<<gg, 256, 0, stream>>>(xb, wob, bo, (void*)out, M_, E_, E_);
}

// Round 2
// 406.158 us; speedup vs baseline: 1.5918x; 1.5918x over previous
//
#include <hip/hip_runtime.h>
#include <hip/hip_bf16.h>
#include <stdint.h>

#define B_   2
#define N_   2048
#define H_   16
#define DQK_ 128
#define DV_  128
#define E_   2048
#define CH_  64
#define NC_  32
#define M_   (B_*N_)   // 4096

using bf16x8 = __attribute__((ext_vector_type(8))) __bf16;
using f32x4  = __attribute__((ext_vector_type(4))) float;
typedef __hip_bfloat16 bf16_t;

__device__ __forceinline__ void gload_lds16(const void* g, void* l) {
  __builtin_amdgcn_global_load_lds(
      (const __attribute__((address_space(1))) void*)(uintptr_t)g,
      (__attribute__((address_space(3))) void*)(uint32_t)(uintptr_t)l,
      16, 0, 0);
}

__device__ __forceinline__ float head_log2g(int h) {
  return (float)(log2(1.0 - exp2((double)(-5 - h))));
}

// ---------------- f32 -> bf16 convert ----------------
__global__ void cvt_bf16_kernel(const float* __restrict__ src,
                                bf16_t* __restrict__ dst, int n4) {
  int i = blockIdx.x * 256 + threadIdx.x;
  if (i >= n4) return;
  float4 v = ((const float4*)src)[i];
  bf16_t o0 = __float2bfloat16(v.x), o1 = __float2bfloat16(v.y);
  bf16_t o2 = __float2bfloat16(v.z), o3 = __float2bfloat16(v.w);
  ushort4 p;
  p.x = *(unsigned short*)&o0; p.y = *(unsigned short*)&o1;
  p.z = *(unsigned short*)&o2; p.w = *(unsigned short*)&o3;
  ((ushort4*)dst)[i] = p;
}

// ---------------- GEMM: C[M,N] = A[M,K] @ Bw[N,K]^T + bias ----------------
template<bool OUT_BF16>
__global__ __launch_bounds__(256)
void gemm_kernel(const bf16_t* __restrict__ A, const bf16_t* __restrict__ Bw,
                 const float* __restrict__ bias, void* __restrict__ Cout,
                 int M, int N, int K) {
  __shared__ alignas(16) bf16_t As[128*32];
  __shared__ alignas(16) bf16_t Bs[128*32];
  const int tid = threadIdx.x;
  const int wave = tid >> 6, lane = tid & 63;
  const int wr = wave >> 1, wc = wave & 1;
  const int l16 = lane & 15, lhi = lane >> 4;
  const int row0 = blockIdx.y * 128, col0 = blockIdx.x * 128;
  const int srow = tid >> 2;
  const int skoff = (tid & 3) * 8;

  f32x4 acc[4][4] = {};

  for (int k0 = 0; k0 < K; k0 += 32) {
    __syncthreads();
    gload_lds16(A  + (size_t)(row0 +      srow)*K + k0 + skoff, (char*)As +        wave*1024);
    gload_lds16(A  + (size_t)(row0 + 64 + srow)*K + k0 + skoff, (char*)As + 4096 + wave*1024);
    gload_lds16(Bw + (size_t)(col0 +      srow)*K + k0 + skoff, (char*)Bs +        wave*1024);
    gload_lds16(Bw + (size_t)(col0 + 64 + srow)*K + k0 + skoff, (char*)Bs + 4096 + wave*1024);
    __syncthreads();
    bf16x8 a[4], b[4];
#pragma unroll
    for (int m = 0; m < 4; m++)
      a[m] = *(const bf16x8*)((const char*)As + ((wr*64 + m*16 + l16)*32 + lhi*8)*2);
#pragma unroll
    for (int n = 0; n < 4; n++)
      b[n] = *(const bf16x8*)((const char*)Bs + ((wc*64 + n*16 + l16)*32 + lhi*8)*2);
#pragma unroll
    for (int m = 0; m < 4; m++)
#pragma unroll
      for (int n = 0; n < 4; n++)
        acc[m][n] = __builtin_amdgcn_mfma_f32_16x16x32_bf16(a[m], b[n], acc[m][n], 0, 0, 0);
  }

#pragma unroll
  for (int n = 0; n < 4; n++) {
    const int col = col0 + wc*64 + n*16 + l16;
    const float bv = bias[col];
#pragma unroll
    for (int m = 0; m < 4; m++) {
      const int rbase = row0 + wr*64 + m*16 + lhi*4;
#pragma unroll
      for (int j = 0; j < 4; j++) {
        float v = acc[m][n][j] + bv;
        if (OUT_BF16) ((bf16_t*)Cout)[(size_t)(rbase + j)*N + col] = __float2bfloat16(v);
        else          ((float*)Cout)[(size_t)(rbase + j)*N + col] = v;
      }
    }
  }
}

// ---------------- rotary (xPos) on q,k in-place; k scaled 1/sqrt(dqk) -------
__global__ void rotary_kernel(bf16_t* __restrict__ q, bf16_t* __restrict__ k,
                              const int* __restrict__ startp) {
  int t = blockIdx.x * 256 + threadIdx.x;
  if (t >= B_*N_*H_*16) return;
  int dg = t & 15;
  int rest = t >> 4;
  int n = (rest >> 4) & (N_ - 1);
  float pos = (float)(startp[0] + n);
  size_t base = (size_t)rest * 128 + dg * 8;
  bf16x8 qv = *(const bf16x8*)(q + base);
  bf16x8 kv = *(const bf16x8*)(k + base);
  bf16x8 qo, ko;
  const float KS = 0.08838834764831843f;
#pragma unroll
  for (int p = 0; p < 4; p++) {
    int j = dg * 4 + p;
    float theta = exp2f(-13.287712379549449f * ((float)j * (1.0f/63.0f)));
    float ang = pos * theta;
    float s, c;
    sincosf(ang, &s, &c);
    float qa = (float)qv[2*p], qb = (float)qv[2*p+1];
    float ka = (float)kv[2*p], kb = (float)kv[2*p+1];
    qo[2*p]   = (__bf16)(qa*c - qb*s);
    qo[2*p+1] = (__bf16)(qb*c + qa*s);
    ko[2*p]   = (__bf16)((ka*c - kb*s) * KS);
    ko[2*p+1] = (__bf16)((kb*c + ka*s) * KS);
  }
  *(bf16x8*)(q + base) = qo;
  *(bf16x8*)(k + base) = ko;
}

// ---------------- per-chunk KV^T = V^T . K'  (parallel over b,h,chunk) ------
// Output KVT[bh][ch][e][d] bf16.  K' has kv_decay gamma^(63-j) folded in.
__global__ __launch_bounds__(256)
void chunk_kvt_kernel(const bf16_t* __restrict__ kb, const bf16_t* __restrict__ vb,
                      bf16_t* __restrict__ kvt) {
  __shared__ alignas(16) char lds[32768];
  char* vts = lds;            // V^T [e:128][j:64] bf16, swizzled
  char* kts = lds + 16384;    // K'^T [d:128][j:64] bf16, swizzled

  const int tid = threadIdx.x, wave = tid >> 6, lane = tid & 63;
  const int l16 = lane & 15, lhi = lane >> 4;
  const int blk = blockIdx.x;              // bh*NC + ch
  const int bh = blk >> 5, ch = blk & 31;
  const int h = bh & (H_ - 1);
  const float log2g = head_log2g(h);
  const int n0 = ch * 64;

  const size_t rowstride = (size_t)H_ * 128;
  const size_t bhbase = (size_t)(bh >> 4) * N_ * rowstride + (size_t)h * 128;

#pragma unroll
  for (int it = 0; it < 4; it++) {
    int j = it*16 + (tid >> 4);
    int e0 = (tid & 15) * 8;
    bf16x8 vv = *(const bf16x8*)(vb + bhbase + (size_t)(n0 + j)*rowstride + e0);
    bf16x8 kk = *(const bf16x8*)(kb + bhbase + (size_t)(n0 + j)*rowstride + e0);
    float kvd = exp2f((float)(63 - j) * log2g);
#pragma unroll
    for (int m = 0; m < 8; m++) {
      int e = e0 + m;
      *(__bf16*)(vts + e*128 + ((j*2) ^ ((e&7)<<4))) = vv[m];
      *(__bf16*)(kts + e*128 + ((j*2) ^ ((e&7)<<4))) = (__bf16)((float)kk[m] * kvd);
    }
  }
  __syncthreads();

  f32x4 acc[2][8] = {};
#pragma unroll
  for (int kk2 = 0; kk2 < 2; kk2++) {
#pragma unroll
    for (int et = 0; et < 2; et++) {
      int e = (2*wave + et)*16 + l16;
      bf16x8 vf = *(const bf16x8*)(vts + e*128 + (((kk2*32 + lhi*8)*2) ^ ((e&7)<<4)));
#pragma unroll
      for (int dt = 0; dt < 8; dt++) {
        int d = dt*16 + l16;
        bf16x8 kf = *(const bf16x8*)(kts + d*128 + (((kk2*32 + lhi*8)*2) ^ ((d&7)<<4)));
        acc[et][dt] = __builtin_amdgcn_mfma_f32_16x16x32_bf16(vf, kf, acc[et][dt], 0, 0, 0);
      }
    }
  }

  const size_t obase = (size_t)blk * 16384;
#pragma unroll
  for (int et = 0; et < 2; et++)
#pragma unroll
    for (int dt = 0; dt < 8; dt++)
#pragma unroll
      for (int j = 0; j < 4; j++) {
        int e = (2*wave + et)*16 + lhi*4 + j;
        int d = dt*16 + l16;
        kvt[obase + e*128 + d] = __float2bfloat16(acc[et][dt][j]);
      }
}

// ---------------- state scan over chunks (element-parallel) ----------------
// S_entry(0)=prev; S_entry(t+1) = S_entry(t)*gamma^64 + KV_t.  Writes bf16
// entering-state per chunk (sbft[bh][ch][e][d]) and final f32 state [bh][d][e].
__global__ __launch_bounds__(256)
void state_scan_kernel(const bf16_t* __restrict__ kvt, const float* __restrict__ prev,
                       bf16_t* __restrict__ sbft, float* __restrict__ out_state) {
  int p = blockIdx.x * 256 + threadIdx.x;     // over B*H*16384
  int bh = p >> 14;
  int ed = p & 16383;
  int e = ed >> 7, d = ed & 127;
  int h = bh & (H_ - 1);
  const float cdecay = exp2f(64.0f * head_log2g(h));

  float S = prev[(size_t)bh*16384 + d*128 + e];
  size_t boff = (size_t)bh * (NC_*16384) + ed;
  for (int ch = 0; ch < NC_; ch++) {
    sbft[boff] = __float2bfloat16(S);
    S = S * cdecay + __bfloat162float(kvt[boff]);
    boff += 16384;
  }
  out_state[(size_t)bh*16384 + d*128 + e] = S;
}

// ---------------- per-chunk output (parallel over b,h,chunk) ----------------
// o = (q k^T ∘ D) @ v + (q @ S_entry) * cross_decay
__global__ __launch_bounds__(256)
void chunk_out_kernel(const bf16_t* __restrict__ qb, const bf16_t* __restrict__ kb,
                      const bf16_t* __restrict__ vb, const bf16_t* __restrict__ sbft,
                      float* __restrict__ o_pre) {
  __shared__ alignas(16) char lds[24576];
  char* vts = lds;            // V^T [e:128][j:64] bf16, swizzled
  char* ats = lds + 16384;    // att [i:64][j:64] bf16, swizzled

  const int tid = threadIdx.x, wave = tid >> 6, lane = tid & 63;
  const int l16 = lane & 15, lhi = lane >> 4;
  const int blk = blockIdx.x;              // bh*NC + ch
  const int bh = blk >> 5, ch = blk & 31;
  const int h = bh & (H_ - 1);
  const float log2g = head_log2g(h);
  const int n0 = ch * 64;

  const size_t rowstride = (size_t)H_ * 128;
  const size_t bhbase = (size_t)(bh >> 4) * N_ * rowstride + (size_t)h * 128;
  const bf16_t* Srow = sbft + (size_t)blk * 16384;   // [e][d]

  // V^T into LDS
#pragma unroll
  for (int it = 0; it < 4; it++) {
    int j = it*16 + (tid >> 4);
    int e0 = (tid & 15) * 8;
    bf16x8 vv = *(const bf16x8*)(vb + bhbase + (size_t)(n0 + j)*rowstride + e0);
#pragma unroll
    for (int m = 0; m < 8; m++) {
      int e = e0 + m;
      *(__bf16*)(vts + e*128 + ((j*2) ^ ((e&7)<<4))) = vv[m];
    }
  }

  // q fragments (A operand, rows i = wave*16 + l16)
  bf16x8 qf[4];
#pragma unroll
  for (int dk = 0; dk < 4; dk++)
    qf[dk] = *(const bf16x8*)(qb + bhbase + (size_t)(n0 + wave*16 + l16)*rowstride + dk*32 + lhi*8);

  // att = (q k^T) * Dmat
  f32x4 aacc[4] = {};
#pragma unroll
  for (int jt = 0; jt < 4; jt++) {
#pragma unroll
    for (int dk = 0; dk < 4; dk++) {
      bf16x8 kf = *(const bf16x8*)(kb + bhbase + (size_t)(n0 + jt*16 + l16)*rowstride + dk*32 + lhi*8);
      aacc[jt] = __builtin_amdgcn_mfma_f32_16x16x32_bf16(qf[dk], kf, aacc[jt], 0, 0, 0);
    }
  }
#pragma unroll
  for (int jt = 0; jt < 4; jt++)
#pragma unroll
    for (int j = 0; j < 4; j++) {
      int i = wave*16 + lhi*4 + j;
      int jc = jt*16 + l16;
      aacc[jt][j] *= (i >= jc) ? exp2f((float)(i - jc) * log2g) : 0.0f;
    }

  // att -> LDS
#pragma unroll
  for (int jt = 0; jt < 4; jt++)
#pragma unroll
    for (int j = 0; j < 4; j++) {
      int i = wave*16 + lhi*4 + j;
      int jc = jt*16 + l16;
      *(__bf16*)(ats + i*128 + ((jc*2) ^ ((i&7)<<4))) = (__bf16)aacc[jt][j];
    }
  __syncthreads();

  // oacc = q @ S_entry (B frags straight from global), * cross_decay
  f32x4 oacc[8] = {};
#pragma unroll
  for (int et = 0; et < 8; et++) {
#pragma unroll
    for (int dk = 0; dk < 4; dk++) {
      int e = et*16 + l16;
      bf16x8 sf = *(const bf16x8*)(Srow + e*128 + dk*32 + lhi*8);
      oacc[et] = __builtin_amdgcn_mfma_f32_16x16x32_bf16(qf[dk], sf, oacc[et], 0, 0, 0);
    }
  }
#pragma unroll
  for (int j = 0; j < 4; j++) {
    int i = wave*16 + lhi*4 + j;
    float f = exp2f((float)(i + 1) * log2g);
#pragma unroll
    for (int et = 0; et < 8; et++) oacc[et][j] *= f;
  }

  // oacc += att @ V
#pragma unroll
  for (int kk2 = 0; kk2 < 2; kk2++) {
    int i = wave*16 + l16;
    bf16x8 af = *(const bf16x8*)(ats + i*128 + (((kk2*32 + lhi*8)*2) ^ ((i&7)<<4)));
#pragma unroll
    for (int et = 0; et < 8; et++) {
      int e = et*16 + l16;
      bf16x8 vf = *(const bf16x8*)(vts + e*128 + (((kk2*32 + lhi*8)*2) ^ ((e&7)<<4)));
      oacc[et] = __builtin_amdgcn_mfma_f32_16x16x32_bf16(af, vf, oacc[et], 0, 0, 0);
    }
  }

  // store o (pre-groupnorm, f32)
#pragma unroll
  for (int et = 0; et < 8; et++)
#pragma unroll
    for (int j = 0; j < 4; j++) {
      int i = wave*16 + lhi*4 + j;
      o_pre[bhbase + (size_t)(n0 + i)*rowstride + et*16 + l16] = oacc[et][j];
    }
}

// ---------------- GroupNorm(per head, no affine) * SiLU(gate) ----------------
__global__ __launch_bounds__(256)
void gn_gate_kernel(const float* __restrict__ o_pre, const bf16_t* __restrict__ gbuf,
                    bf16_t* __restrict__ gated) {
  int row = blockIdx.x * 4 + (threadIdx.x >> 6);
  int lane = threadIdx.x & 63;
  size_t base = (size_t)row * 128 + lane * 2;
  float2 xv = *(const float2*)(o_pre + base);
  float s = xv.x + xv.y, ss = xv.x*xv.x + xv.y*xv.y;
#pragma unroll
  for (int off = 1; off < 64; off <<= 1) {
    s  += __shfl_xor(s, off);
    ss += __shfl_xor(ss, off);
  }
  float mu  = s * (1.0f/128.0f);
  float inv = rsqrtf(ss * (1.0f/128.0f) - mu*mu + 1e-6f);
  float g0 = __bfloat162float(gbuf[base]),  g1 = __bfloat162float(gbuf[base+1]);
  float r0 = (xv.x - mu) * inv * (g0 / (1.0f + expf(-g0)));
  float r1 = (xv.y - mu) * inv * (g1 / (1.0f + expf(-g1)));
  gated[base]   = __float2bfloat16(r0);
  gated[base+1] = __float2bfloat16(r1);
}

// ---------------- launch ----------------
extern "C" void kernel_launch(void* const* d_in, const int* in_sizes, int n_in,
                              void* d_out, int out_size, void* d_ws, size_t ws_size,
                              hipStream_t stream) {
  const float* x    = (const float*)d_in[0];
  const float* prev = (const float*)d_in[1];
  const float* Wq = (const float*)d_in[2];  const float* bq = (const float*)d_in[3];
  const float* Wk = (const float*)d_in[4];  const float* bk = (const float*)d_in[5];
  const float* Wv = (const float*)d_in[6];  const float* bv = (const float*)d_in[7];
  const float* Wg = (const float*)d_in[8];  const float* bg = (const float*)d_in[9];
  const float* Wo = (const float*)d_in[10]; const float* bo = (const float*)d_in[11];
  const int* startp = (const int*)d_in[12];

  float* out = (float*)d_out;                               // B*N*E
  float* out_state = out + (size_t)B_*N_*E_;                // B*H*DQK*DV

  char* w = (char*)d_ws;
  const size_t XN = (size_t)B_*N_*E_;       // 8388608
  const size_t WN = (size_t)E_*E_;          // 4194304
  bf16_t* xb   = (bf16_t*)w;             w += XN*2;   // reused as `gated`
  bf16_t* qbuf = (bf16_t*)w;             w += XN*2;
  bf16_t* kbuf = (bf16_t*)w;             w += XN*2;
  bf16_t* vbuf = (bf16_t*)w;             w += XN*2;
  bf16_t* gbuf = (bf16_t*)w;             w += XN*2;
  bf16_t* wob  = (bf16_t*)w;             w += WN*2;
  char*   proj_w = w;                    // wq/wk/wv/wg: 32MB, dead after GEMMs
  bf16_t* wqb  = (bf16_t*)w;             w += WN*2;
  bf16_t* wkb  = (bf16_t*)w;             w += WN*2;
  bf16_t* wvb  = (bf16_t*)w;             w += WN*2;
  bf16_t* wgb  = (bf16_t*)w;             w += WN*2;
  bf16_t* sbft = (bf16_t*)w;             w += (size_t)B_*H_*NC_*16384*2; // 32MB
  // aliases over proj_w (32MB): KVT bf16 (kernels A,B) then o_pre f32 (C, gn)
  bf16_t* kvt   = (bf16_t*)proj_w;
  float*  o_pre = (float*)proj_w;

  cvt_bf16_kernel<<<(int)(XN/4/256), 256, 0, stream>>>(x,  xb,  (int)(XN/4));
  cvt_bf16_kernel<<<(int)(WN/4/256), 256, 0, stream>>>(Wq, wqb, (int)(WN/4));
  cvt_bf16_kernel<<<(int)(WN/4/256), 256, 0, stream>>>(Wk, wkb, (int)(WN/4));
  cvt_bf16_kernel<<<(int)(WN/4/256), 256, 0, stream>>>(Wv, wvb, (int)(WN/4));
  cvt_bf16_kernel<<<(int)(WN/4/256), 256, 0, stream>>>(Wg, wgb, (int)(WN/4));
  cvt_bf16_kernel<<<(int)(WN/4/256), 256, 0, stream>>>(Wo, wob, (int)(WN/4));

  dim3 gg(E_/128, M_/128);  // (16, 32)
  gemm_kernel<true><<<gg, 256, 0, stream>>>(xb, wqb, bq, (void*)qbuf, M_, E_, E_);
  gemm_kernel<true><<<gg, 256, 0, stream>>>(xb, wkb, bk, (void*)kbuf, M_, E_, E_);
  gemm_kernel<true><<<gg, 256, 0, stream>>>(xb, wvb, bv, (void*)vbuf, M_, E_, E_);
  gemm_kernel<true><<<gg, 256, 0, stream>>>(xb, wgb, bg, (void*)gbuf, M_, E_, E_);

  rotary_kernel<<<(B_*N_*H_*16)/256, 256, 0, stream>>>(qbuf, kbuf, startp);

  chunk_kvt_kernel<<<B_*H_*NC_, 256, 0, stream>>>(kbuf, vbuf, kvt);
  state_scan_kernel<<<(B_*H_*16384)/256, 256, 0, stream>>>(kvt, prev, sbft, out_state);
  chunk_out_kernel<<<B_*H_*NC_, 256, 0, stream>>>(qbuf, kbuf, vbuf, sbft, o_pre);

  gn_gate_kernel<<<(B_*N_*H_)/4, 256, 0, stream>>>(o_pre, gbuf, xb /*gated*/);

  gemm_kernel<false><<<gg, 256, 0, stream>>>(xb, wob, bo, (void*)out, M_, E_, E_);
}

// Round 4
// 325.494 us; speedup vs baseline: 1.9862x; 1.2478x over previous
//
#include <hip/hip_runtime.h>
#include <hip/hip_bf16.h>
#include <stdint.h>

#define B_   2
#define N_   2048
#define H_   16
#define DQK_ 128
#define DV_  128
#define E_   2048
#define CH_  64
#define NC_  32
#define M_   (B_*N_)   // 4096
#define QKVG_LD 8192

using bf16x8 = __attribute__((ext_vector_type(8))) __bf16;
using f32x4  = __attribute__((ext_vector_type(4))) float;
typedef __hip_bfloat16 bf16_t;

__device__ __forceinline__ void gload_lds16(const void* g, void* l) {
  __builtin_amdgcn_global_load_lds(
      (const __attribute__((address_space(1))) void*)(uintptr_t)g,
      (__attribute__((address_space(3))) void*)(uint32_t)(uintptr_t)l,
      16, 0, 0);
}

__device__ __forceinline__ float head_log2g(int h) {
  return (float)(log2(1.0 - exp2((double)(-5 - h))));
}

// ---------------- f32 -> bf16 convert ----------------
__global__ void cvt_bf16_kernel(const float* __restrict__ src,
                                bf16_t* __restrict__ dst, int n4) {
  int i = blockIdx.x * 256 + threadIdx.x;
  if (i >= n4) return;
  float4 v = ((const float4*)src)[i];
  bf16_t o0 = __float2bfloat16(v.x), o1 = __float2bfloat16(v.y);
  bf16_t o2 = __float2bfloat16(v.z), o3 = __float2bfloat16(v.w);
  ushort4 p;
  p.x = *(unsigned short*)&o0; p.y = *(unsigned short*)&o1;
  p.z = *(unsigned short*)&o2; p.w = *(unsigned short*)&o3;
  ((ushort4*)dst)[i] = p;
}

// ============ 256x256 8-phase GEMM: C[M,*] = A[M,K] @ Bw[N,K]^T + bias ======
// 8 waves (2M x 4N), BK=64, 128KB LDS double-buffer.
// LDS: A tiles @0 (2 x 32KB), B tiles @65536 (2 x 32KB). Tile = [256][64] bf16,
// rows 128B, XOR-swizzled (byte ^= (row&7)<<4) via pre-swizzled global source.
// Half-tile stream per K-tile: region order [Bh0, Bh1, Ah0, Ah1]; stage at
// phase p of kt targets half 4*kt+p+6 (p0,p1 -> next buf A; p2,p3 -> cur-parity
// buf B, whose LDS reads completed at phase 0). vmcnt(4) at K-tile boundary.
// Every barrier is paired with a memory-clobber fence so LDS reads/writes
// cannot be compiler-hoisted across the sync points (race fix, r3->r4).
template<bool OUT_BF16>
__global__ __launch_bounds__(512, 2)
void gemm8_kernel(const bf16_t* __restrict__ A, const bf16_t* __restrict__ Bw,
                  const float* __restrict__ bias, void* __restrict__ Cout,
                  int K, int ldc, int tilesM) {
  extern __shared__ char smem[];   // 131072 bytes
  const int nwg = gridDim.x;
  const int bid = blockIdx.x;
  const int cpx = nwg >> 3;                      // nwg % 8 == 0 guaranteed
  const int swz = (bid & 7) * cpx + (bid >> 3);  // XCD-bijective
  const int tm = swz % tilesM, tn = swz / tilesM;
  const int rowT0 = tm * 256, colT0 = tn * 256;
  const int tid = threadIdx.x, wave = tid >> 6, lane = tid & 63;
  const int wr = wave >> 2, wc = wave & 3;
  const int l16 = lane & 15, lhi = lane >> 4;
  const int NKT = K >> 6;

  // staging source pre-swizzle: thread t covers dest bytes t*16 (+8192)
  const int sw = ((tid & 7) * 16) ^ (((tid >> 3) & 7) << 4);
  const size_t aOff = (size_t)(rowT0 + (tid >> 3)) * K + (sw >> 1);
  const size_t bOff = (size_t)(colT0 + (tid >> 3)) * K + (sw >> 1);
  const uint32_t wl = wave * 1024;

  auto stage = [&](int h) {
    const int ktp = h >> 2, r = h & 3, buf = ktp & 1;
    const int k0 = ktp << 6;
    const int half = (r < 2) ? r : (r - 2);
    const bf16_t* src = (r < 2) ? Bw : A;
    const size_t off = (r < 2) ? bOff : aOff;
    const uint32_t base = ((r < 2) ? 65536u : 0u) + buf * 32768 + half * 16384 + wl;
#pragma unroll
    for (int L = 0; L < 2; L++)
      gload_lds16(src + off + (size_t)(half * 128 + L * 64) * K + k0,
                  smem + base + L * 8192);
  };

  // prologue: halves 0..5 (kt0 full + kt1 B)
  for (int h = 0; h < 6; h++) stage(h);
  asm volatile("s_waitcnt vmcnt(4)" ::: "memory");
  __builtin_amdgcn_s_barrier();
  asm volatile("" ::: "memory");
  __builtin_amdgcn_sched_barrier(0);

  f32x4 acc[8][4] = {};
  bf16x8 bfr[4][2];

  for (int kt = 0; kt < NKT; kt++) {
    const int cur = kt & 1;
    const uint32_t aB = cur * 32768;
    const uint32_t bB = 65536 + cur * 32768;
#pragma unroll
    for (int p = 0; p < 4; p++) {
      bf16x8 afr[2][2];
      if (p == 0) {
#pragma unroll
        for (int n = 0; n < 4; n++) {
          const int r = wc * 64 + n * 16 + l16;
#pragma unroll
          for (int ks = 0; ks < 2; ks++) {
            const int cb = ks * 64 + lhi * 16;
            bfr[n][ks] = *(const bf16x8*)(smem + bB + r * 128 + (cb ^ ((r & 7) << 4)));
          }
        }
      }
#pragma unroll
      for (int mm = 0; mm < 2; mm++) {
        const int r = wr * 128 + p * 32 + mm * 16 + l16;
#pragma unroll
        for (int ks = 0; ks < 2; ks++) {
          const int cb = ks * 64 + lhi * 16;
          afr[mm][ks] = *(const bf16x8*)(smem + aB + r * 128 + (cb ^ ((r & 7) << 4)));
        }
      }
      const int h = 4 * kt + p + 6;
      if (h < 4 * NKT) stage(h);
      __builtin_amdgcn_s_barrier();
      asm volatile("s_waitcnt lgkmcnt(0)" ::: "memory");
      __builtin_amdgcn_sched_barrier(0);
      __builtin_amdgcn_s_setprio(1);
#pragma unroll
      for (int mm = 0; mm < 2; mm++)
#pragma unroll
        for (int n = 0; n < 4; n++)
#pragma unroll
          for (int ks = 0; ks < 2; ks++)
            acc[2 * p + mm][n] = __builtin_amdgcn_mfma_f32_16x16x32_bf16(
                afr[mm][ks], bfr[n][ks], acc[2 * p + mm][n], 0, 0, 0);
      __builtin_amdgcn_s_setprio(0);
      if (p == 3) {
        if (kt < NKT - 2)       asm volatile("s_waitcnt vmcnt(4)" ::: "memory");
        else if (kt == NKT - 2) asm volatile("s_waitcnt vmcnt(0)" ::: "memory");
      }
      __builtin_amdgcn_s_barrier();
      asm volatile("" ::: "memory");
      __builtin_amdgcn_sched_barrier(0);
    }
  }

#pragma unroll
  for (int m = 0; m < 8; m++) {
    const int rbase = rowT0 + wr * 128 + m * 16 + lhi * 4;
#pragma unroll
    for (int n = 0; n < 4; n++) {
      const int col = colT0 + wc * 64 + n * 16 + l16;
      const float bv = bias[col];
#pragma unroll
      for (int j = 0; j < 4; j++) {
        float v = acc[m][n][j] + bv;
        if (OUT_BF16) ((bf16_t*)Cout)[(size_t)(rbase + j) * ldc + col] = __float2bfloat16(v);
        else          ((float*)Cout)[(size_t)(rbase + j) * ldc + col] = v;
      }
    }
  }
}

// ---------------- rotary (xPos) on q,k in-place; k scaled 1/sqrt(dqk) -------
// q,k live in the fused qkvg buffer with row stride 8192.
__global__ void rotary_kernel(bf16_t* __restrict__ q, bf16_t* __restrict__ k,
                              const int* __restrict__ startp) {
  int t = blockIdx.x * 256 + threadIdx.x;
  if (t >= B_*N_*H_*16) return;
  int dg = t & 15;
  int rest = t >> 4;                          // (b*N+n)*H + h
  int n = (rest >> 4) & (N_ - 1);
  int h = rest & 15;
  float pos = (float)(startp[0] + n);
  size_t base = (size_t)(rest >> 4) * QKVG_LD + h * 128 + dg * 8;
  bf16x8 qv = *(const bf16x8*)(q + base);
  bf16x8 kv = *(const bf16x8*)(k + base);
  bf16x8 qo, ko;
  const float KS = 0.08838834764831843f;
#pragma unroll
  for (int p = 0; p < 4; p++) {
    int j = dg * 4 + p;
    float theta = exp2f(-13.287712379549449f * ((float)j * (1.0f/63.0f)));
    float ang = pos * theta;
    float s, c;
    sincosf(ang, &s, &c);
    float qa = (float)qv[2*p], qb = (float)qv[2*p+1];
    float ka = (float)kv[2*p], kb = (float)kv[2*p+1];
    qo[2*p]   = (__bf16)(qa*c - qb*s);
    qo[2*p+1] = (__bf16)(qb*c + qa*s);
    ko[2*p]   = (__bf16)((ka*c - kb*s) * KS);
    ko[2*p+1] = (__bf16)((kb*c + ka*s) * KS);
  }
  *(bf16x8*)(q + base) = qo;
  *(bf16x8*)(k + base) = ko;
}

// ---------------- per-chunk KV^T = V^T . K'  (parallel over b,h,chunk) ------
__global__ __launch_bounds__(256)
void chunk_kvt_kernel(const bf16_t* __restrict__ kb, const bf16_t* __restrict__ vb,
                      bf16_t* __restrict__ kvt) {
  __shared__ alignas(16) char lds[32768];
  char* vts = lds;
  char* kts = lds + 16384;

  const int tid = threadIdx.x, wave = tid >> 6, lane = tid & 63;
  const int l16 = lane & 15, lhi = lane >> 4;
  const int blk = blockIdx.x;              // bh*NC + ch
  const int bh = blk >> 5, ch = blk & 31;
  const int h = bh & (H_ - 1);
  const float log2g = head_log2g(h);
  const int n0 = ch * 64;

  const size_t bhbase = (size_t)(bh >> 4) * N_ * QKVG_LD + (size_t)h * 128;

#pragma unroll
  for (int it = 0; it < 4; it++) {
    int j = it*16 + (tid >> 4);
    int e0 = (tid & 15) * 8;
    bf16x8 vv = *(const bf16x8*)(vb + bhbase + (size_t)(n0 + j)*QKVG_LD + e0);
    bf16x8 kk = *(const bf16x8*)(kb + bhbase + (size_t)(n0 + j)*QKVG_LD + e0);
    float kvd = exp2f((float)(63 - j) * log2g);
#pragma unroll
    for (int m = 0; m < 8; m++) {
      int e = e0 + m;
      *(__bf16*)(vts + e*128 + ((j*2) ^ ((e&7)<<4))) = vv[m];
      *(__bf16*)(kts + e*128 + ((j*2) ^ ((e&7)<<4))) = (__bf16)((float)kk[m] * kvd);
    }
  }
  __syncthreads();

  f32x4 acc[2][8] = {};
#pragma unroll
  for (int kk2 = 0; kk2 < 2; kk2++) {
#pragma unroll
    for (int et = 0; et < 2; et++) {
      int e = (2*wave + et)*16 + l16;
      bf16x8 vf = *(const bf16x8*)(vts + e*128 + (((kk2*32 + lhi*8)*2) ^ ((e&7)<<4)));
#pragma unroll
      for (int dt = 0; dt < 8; dt++) {
        int d = dt*16 + l16;
        bf16x8 kf = *(const bf16x8*)(kts + d*128 + (((kk2*32 + lhi*8)*2) ^ ((d&7)<<4)));
        acc[et][dt] = __builtin_amdgcn_mfma_f32_16x16x32_bf16(vf, kf, acc[et][dt], 0, 0, 0);
      }
    }
  }

  const size_t obase = (size_t)blk * 16384;
#pragma unroll
  for (int et = 0; et < 2; et++)
#pragma unroll
    for (int dt = 0; dt < 8; dt++)
#pragma unroll
      for (int j = 0; j < 4; j++) {
        int e = (2*wave + et)*16 + lhi*4 + j;
        int d = dt*16 + l16;
        kvt[obase + e*128 + d] = __float2bfloat16(acc[et][dt][j]);
      }
}

// ---------------- state scan over chunks (element-parallel) ----------------
__global__ __launch_bounds__(256)
void state_scan_kernel(const bf16_t* __restrict__ kvt, const float* __restrict__ prev,
                       bf16_t* __restrict__ sbft, float* __restrict__ out_state) {
  int p = blockIdx.x * 256 + threadIdx.x;     // over B*H*16384
  int bh = p >> 14;
  int ed = p & 16383;
  int e = ed >> 7, d = ed & 127;
  int h = bh & (H_ - 1);
  const float cdecay = exp2f(64.0f * head_log2g(h));

  float S = prev[(size_t)bh*16384 + d*128 + e];
  size_t boff = (size_t)bh * (NC_*16384) + ed;
  for (int ch = 0; ch < NC_; ch++) {
    sbft[boff] = __float2bfloat16(S);
    S = S * cdecay + __bfloat162float(kvt[boff]);
    boff += 16384;
  }
  out_state[(size_t)bh*16384 + d*128 + e] = S;
}

// ---------------- per-chunk output (parallel over b,h,chunk) ----------------
__global__ __launch_bounds__(256)
void chunk_out_kernel(const bf16_t* __restrict__ qb, const bf16_t* __restrict__ kb,
                      const bf16_t* __restrict__ vb, const bf16_t* __restrict__ sbft,
                      float* __restrict__ o_pre) {
  __shared__ alignas(16) char lds[24576];
  char* vts = lds;
  char* ats = lds + 16384;

  const int tid = threadIdx.x, wave = tid >> 6, lane = tid & 63;
  const int l16 = lane & 15, lhi = lane >> 4;
  const int blk = blockIdx.x;              // bh*NC + ch
  const int bh = blk >> 5, ch = blk & 31;
  const int h = bh & (H_ - 1);
  const float log2g = head_log2g(h);
  const int n0 = ch * 64;

  const size_t bhbase = (size_t)(bh >> 4) * N_ * QKVG_LD + (size_t)h * 128;
  const size_t obase_o = (size_t)(bh >> 4) * N_ * 2048 + (size_t)h * 128;
  const bf16_t* Srow = sbft + (size_t)blk * 16384;   // [e][d]

#pragma unroll
  for (int it = 0; it < 4; it++) {
    int j = it*16 + (tid >> 4);
    int e0 = (tid & 15) * 8;
    bf16x8 vv = *(const bf16x8*)(vb + bhbase + (size_t)(n0 + j)*QKVG_LD + e0);
#pragma unroll
    for (int m = 0; m < 8; m++) {
      int e = e0 + m;
      *(__bf16*)(vts + e*128 + ((j*2) ^ ((e&7)<<4))) = vv[m];
    }
  }

  bf16x8 qf[4];
#pragma unroll
  for (int dk = 0; dk < 4; dk++)
    qf[dk] = *(const bf16x8*)(qb + bhbase + (size_t)(n0 + wave*16 + l16)*QKVG_LD + dk*32 + lhi*8);

  f32x4 aacc[4] = {};
#pragma unroll
  for (int jt = 0; jt < 4; jt++) {
#pragma unroll
    for (int dk = 0; dk < 4; dk++) {
      bf16x8 kf = *(const bf16x8*)(kb + bhbase + (size_t)(n0 + jt*16 + l16)*QKVG_LD + dk*32 + lhi*8);
      aacc[jt] = __builtin_amdgcn_mfma_f32_16x16x32_bf16(qf[dk], kf, aacc[jt], 0, 0, 0);
    }
  }
#pragma unroll
  for (int jt = 0; jt < 4; jt++)
#pragma unroll
    for (int j = 0; j < 4; j++) {
      int i = wave*16 + lhi*4 + j;
      int jc = jt*16 + l16;
      aacc[jt][j] *= (i >= jc) ? exp2f((float)(i - jc) * log2g) : 0.0f;
    }

#pragma unroll
  for (int jt = 0; jt < 4; jt++)
#pragma unroll
    for (int j = 0; j < 4; j++) {
      int i = wave*16 + lhi*4 + j;
      int jc = jt*16 + l16;
      *(__bf16*)(ats + i*128 + ((jc*2) ^ ((i&7)<<4))) = (__bf16)aacc[jt][j];
    }
  __syncthreads();

  f32x4 oacc[8] = {};
#pragma unroll
  for (int et = 0; et < 8; et++) {
#pragma unroll
    for (int dk = 0; dk < 4; dk++) {
      int e = et*16 + l16;
      bf16x8 sf = *(const bf16x8*)(Srow + e*128 + dk*32 + lhi*8);
      oacc[et] = __builtin_amdgcn_mfma_f32_16x16x32_bf16(qf[dk], sf, oacc[et], 0, 0, 0);
    }
  }
#pragma unroll
  for (int j = 0; j < 4; j++) {
    int i = wave*16 + lhi*4 + j;
    float f = exp2f((float)(i + 1) * log2g);
#pragma unroll
    for (int et = 0; et < 8; et++) oacc[et][j] *= f;
  }

#pragma unroll
  for (int kk2 = 0; kk2 < 2; kk2++) {
    int i = wave*16 + l16;
    bf16x8 af = *(const bf16x8*)(ats + i*128 + (((kk2*32 + lhi*8)*2) ^ ((i&7)<<4)));
#pragma unroll
    for (int et = 0; et < 8; et++) {
      int e = et*16 + l16;
      bf16x8 vf = *(const bf16x8*)(vts + e*128 + (((kk2*32 + lhi*8)*2) ^ ((e&7)<<4)));
      oacc[et] = __builtin_amdgcn_mfma_f32_16x16x32_bf16(af, vf, oacc[et], 0, 0, 0);
    }
  }

#pragma unroll
  for (int et = 0; et < 8; et++)
#pragma unroll
    for (int j = 0; j < 4; j++) {
      int i = wave*16 + lhi*4 + j;
      o_pre[obase_o + (size_t)(n0 + i)*2048 + et*16 + l16] = oacc[et][j];
    }
}

// ---------------- GroupNorm(per head, no affine) * SiLU(gate) ----------------
__global__ __launch_bounds__(256)
void gn_gate_kernel(const float* __restrict__ o_pre, const bf16_t* __restrict__ gbuf,
                    bf16_t* __restrict__ gated) {
  int row = blockIdx.x * 4 + (threadIdx.x >> 6);   // (b*N+n)*H + h
  int lane = threadIdx.x & 63;
  size_t base = (size_t)row * 128 + lane * 2;
  size_t gbase = (size_t)(row >> 4) * QKVG_LD + (size_t)(row & 15) * 128 + lane * 2;
  float2 xv = *(const float2*)(o_pre + base);
  float s = xv.x + xv.y, ss = xv.x*xv.x + xv.y*xv.y;
#pragma unroll
  for (int off = 1; off < 64; off <<= 1) {
    s  += __shfl_xor(s, off);
    ss += __shfl_xor(ss, off);
  }
  float mu  = s * (1.0f/128.0f);
  float inv = rsqrtf(ss * (1.0f/128.0f) - mu*mu + 1e-6f);
  float g0 = __bfloat162float(gbuf[gbase]),  g1 = __bfloat162float(gbuf[gbase+1]);
  float r0 = (xv.x - mu) * inv * (g0 / (1.0f + expf(-g0)));
  float r1 = (xv.y - mu) * inv * (g1 / (1.0f + expf(-g1)));
  gated[base]   = __float2bfloat16(r0);
  gated[base+1] = __float2bfloat16(r1);
}

// ---------------- launch ----------------
extern "C" void kernel_launch(void* const* d_in, const int* in_sizes, int n_in,
                              void* d_out, int out_size, void* d_ws, size_t ws_size,
                              hipStream_t stream) {
  const float* x    = (const float*)d_in[0];
  const float* prev = (const float*)d_in[1];
  const float* Wq = (const float*)d_in[2];  const float* bq = (const float*)d_in[3];
  const float* Wk = (const float*)d_in[4];  const float* bk = (const float*)d_in[5];
  const float* Wv = (const float*)d_in[6];  const float* bv = (const float*)d_in[7];
  const float* Wg = (const float*)d_in[8];  const float* bg = (const float*)d_in[9];
  const float* Wo = (const float*)d_in[10]; const float* bo = (const float*)d_in[11];
  const int* startp = (const int*)d_in[12];

  float* out = (float*)d_out;                               // B*N*E
  float* out_state = out + (size_t)B_*N_*E_;                // B*H*DQK*DV

  char* w = (char*)d_ws;
  const size_t XN = (size_t)B_*N_*E_;       // 8388608
  const size_t WN = (size_t)E_*E_;          // 4194304
  bf16_t* xb   = (bf16_t*)w;             w += XN*2;                  // 16MB (reused as gated)
  bf16_t* qkvg = (bf16_t*)w;             w += (size_t)M_*QKVG_LD*2;  // 64MB
  bf16_t* wob  = (bf16_t*)w;             w += WN*2;                  // 8MB
  char*   wcat_region = w;               w += 4*WN*2;                // 32MB
  bf16_t* wcat = (bf16_t*)wcat_region;
  bf16_t* sbft = (bf16_t*)w;             w += (size_t)B_*H_*NC_*16384*2; // 32MB
  // aliases: kvt bf16 then o_pre f32 over wcat (dead after QKVG GEMM)
  bf16_t* kvt   = (bf16_t*)wcat_region;
  float*  o_pre = (float*)wcat_region;
  float*  bcat  = (float*)sbft;   // 32KB at sbft head; consumed before state_scan writes

  hipFuncSetAttribute(reinterpret_cast<const void*>(gemm8_kernel<true>),
                      hipFuncAttributeMaxDynamicSharedMemorySize, 131072);
  hipFuncSetAttribute(reinterpret_cast<const void*>(gemm8_kernel<false>),
                      hipFuncAttributeMaxDynamicSharedMemorySize, 131072);

  cvt_bf16_kernel<<<(int)(XN/4/256), 256, 0, stream>>>(x,  xb,  (int)(XN/4));
  cvt_bf16_kernel<<<(int)(WN/4/256), 256, 0, stream>>>(Wq, wcat,             (int)(WN/4));
  cvt_bf16_kernel<<<(int)(WN/4/256), 256, 0, stream>>>(Wk, wcat + WN,        (int)(WN/4));
  cvt_bf16_kernel<<<(int)(WN/4/256), 256, 0, stream>>>(Wv, wcat + 2*WN,      (int)(WN/4));
  cvt_bf16_kernel<<<(int)(WN/4/256), 256, 0, stream>>>(Wg, wcat + 3*WN,      (int)(WN/4));
  cvt_bf16_kernel<<<(int)(WN/4/256), 256, 0, stream>>>(Wo, wob, (int)(WN/4));

  hipMemcpyAsync(bcat,        bq, E_*4, hipMemcpyDeviceToDevice, stream);
  hipMemcpyAsync(bcat + E_,   bk, E_*4, hipMemcpyDeviceToDevice, stream);
  hipMemcpyAsync(bcat + 2*E_, bv, E_*4, hipMemcpyDeviceToDevice, stream);
  hipMemcpyAsync(bcat + 3*E_, bg, E_*4, hipMemcpyDeviceToDevice, stream);

  // fused QKVG projection: [4096,2048] @ [8192,2048]^T -> [4096,8192]
  gemm8_kernel<true><<<512, 512, 131072, stream>>>(xb, wcat, bcat, (void*)qkvg,
                                                   E_, QKVG_LD, 16);

  rotary_kernel<<<(B_*N_*H_*16)/256, 256, 0, stream>>>(qkvg, qkvg + 2048, startp);

  chunk_kvt_kernel<<<B_*H_*NC_, 256, 0, stream>>>(qkvg + 2048, qkvg + 4096, kvt);
  state_scan_kernel<<<(B_*H_*16384)/256, 256, 0, stream>>>(kvt, prev, sbft, out_state);
  chunk_out_kernel<<<B_*H_*NC_, 256, 0, stream>>>(qkvg, qkvg + 2048, qkvg + 4096,
                                                  sbft, o_pre);

  gn_gate_kernel<<<(B_*N_*H_)/4, 256, 0, stream>>>(o_pre, qkvg + 6144, xb /*gated*/);

  // output projection: [4096,2048] @ [2048,2048]^T -> [4096,2048] f32
  gemm8_kernel<false><<<128, 512, 131072, stream>>>(xb, wob, bo, (void*)out,
                                                    E_, E_, 16);
}

// Round 5
// 286.363 us; speedup vs baseline: 2.2576x; 1.1367x over previous
//
#include <hip/hip_runtime.h>
#include <hip/hip_bf16.h>
#include <stdint.h>

#define B_   2
#define N_   2048
#define H_   16
#define DQK_ 128
#define DV_  128
#define E_   2048
#define CH_  64
#define NC_  32
#define M_   (B_*N_)   // 4096
#define QKVG_LD 8192

using bf16x8 = __attribute__((ext_vector_type(8))) __bf16;
using f32x4  = __attribute__((ext_vector_type(4))) float;
typedef __hip_bfloat16 bf16_t;

__device__ __forceinline__ void gload_lds16(const void* g, void* l) {
  __builtin_amdgcn_global_load_lds(
      (const __attribute__((address_space(1))) void*)(uintptr_t)g,
      (__attribute__((address_space(3))) void*)(uint32_t)(uintptr_t)l,
      16, 0, 0);
}

__device__ __forceinline__ float head_log2g(int h) {
  return (float)(log2(1.0 - exp2((double)(-5 - h))));
}

__device__ __forceinline__ float bfu2f(unsigned short u) {
  unsigned int t = (unsigned int)u << 16; float f;
  __builtin_memcpy(&f, &t, 4); return f;
}
__device__ __forceinline__ unsigned short f2bfu(float f) {
  bf16_t b = __float2bfloat16(f);
  unsigned short u; __builtin_memcpy(&u, &b, 2); return u;
}

// ---------------- fused f32->bf16 convert for all inputs + bias concat ------
// float4 regions: x (2097152) | Wq,Wk,Wv,Wg -> wcat (4x1048576) | Wo (1048576)
// | bq,bk,bv,bg -> bcat (2048).  Region edges are multiples of 256.
__global__ __launch_bounds__(256)
void cvt_all_kernel(const float* __restrict__ x,
                    const float* __restrict__ Wq, const float* __restrict__ Wk,
                    const float* __restrict__ Wv, const float* __restrict__ Wg,
                    const float* __restrict__ Wo,
                    const float* __restrict__ bq, const float* __restrict__ bk,
                    const float* __restrict__ bv, const float* __restrict__ bg,
                    bf16_t* __restrict__ xb, bf16_t* __restrict__ wcat,
                    bf16_t* __restrict__ wob, float* __restrict__ bcat) {
  const int NX = 2097152, NW = 1048576;
  int g = blockIdx.x * 256 + threadIdx.x;
  const float* s; bf16_t* d; int si, di;
  if (g < NX) { s = x; si = g; d = xb; di = g; }
  else if (g < NX + 4*NW) {
    int t = g - NX; int r = t / NW; si = t - r*NW;
    s = (r==0) ? Wq : (r==1) ? Wk : (r==2) ? Wv : Wg; d = wcat; di = t;
  } else if (g < NX + 5*NW) {
    si = g - NX - 4*NW; s = Wo; d = wob; di = si;
  } else {
    int j = g - (NX + 5*NW);                 // 0..2047
    int which = j >> 9, i = j & 511;
    const float* bs = (which==0) ? bq : (which==1) ? bk : (which==2) ? bv : bg;
    ((float4*)bcat)[which*512 + i] = ((const float4*)bs)[i];
    return;
  }
  float4 v = ((const float4*)s)[si];
  ushort4 p;
  p.x = f2bfu(v.x); p.y = f2bfu(v.y); p.z = f2bfu(v.z); p.w = f2bfu(v.w);
  ((ushort4*)d)[di] = p;
}

// ============ 256xBN 8-phase GEMM: C = A[M,K] @ Bw[N,K]^T + bias ============
// BN = 64*NSUB (NSUB=4: 256x256, NSUB=2: 256x128). 8 waves (2M x 4N), BK=64,
// double-buffered LDS: A @0 (2x32KB), B @65536 (2 x 8192*NSUB bytes).
// Rows 128B, XOR-swizzled (byte ^= (row&7)<<4) via pre-swizzled global source.
// Half-tile stream per K-tile: [B0,B1,A0,A1], stage offset +6.
// Waits: p2 vmcnt(6|5) [guarantees next-tile B landed for the p3-top register
// prefetch], p3 vmcnt(4|2) [K-tile gating], NKT-2 p3 vmcnt(0).
// B-fragment reads split: bnx[0..1] at p3-top (next buf), bfr[2..3] at p0-top.
template<bool OUT_BF16, int NSUB>
__global__ __launch_bounds__(512, 2)
void gemm8_kernel(const bf16_t* __restrict__ A, const bf16_t* __restrict__ Bw,
                  const float* __restrict__ bias, void* __restrict__ Cout,
                  int K, int ldc, int tilesM) {
  extern __shared__ char smem[];
  const int nwg = gridDim.x;
  const int bid = blockIdx.x;
  const int cpx = nwg >> 3;                      // nwg % 8 == 0 guaranteed
  const int swz = (bid & 7) * cpx + (bid >> 3);  // XCD-bijective
  const int tm = swz % tilesM, tn = swz / tilesM;
  const int rowT0 = tm * 256, colT0 = tn * (64 * NSUB);
  const int tid = threadIdx.x, wave = tid >> 6, lane = tid & 63;
  const int wr = wave >> 2, wc = wave & 3;
  const int l16 = lane & 15, lhi = lane >> 4;
  const int NKT = K >> 6;

  // staging source pre-swizzle: thread t covers dest bytes t*16 within a half
  const int sw = ((tid & 7) * 16) ^ (((tid >> 3) & 7) << 4);
  const size_t aOff = (size_t)(rowT0 + (tid >> 3)) * K + (sw >> 1);
  const size_t bOff = (size_t)(colT0 + (tid >> 3)) * K + (sw >> 1);
  const uint32_t wl = wave * 1024;

  auto stage = [&](int h) {
    const int ktp = h >> 2, r = h & 3, buf = ktp & 1;
    const int k0 = ktp << 6;
    if (r < 2) {                               // B half r
      const uint32_t base = 65536u + buf * (8192u*NSUB) + r * (4096u*NSUB) + wl;
#pragma unroll
      for (int L = 0; L < NSUB/2; L++)
        gload_lds16(Bw + bOff + (size_t)(r * (NSUB*32) + L * 64) * K + k0,
                    smem + base + L * 8192);
    } else {                                   // A half r-2
      const int half = r - 2;
      const uint32_t base = buf * 32768u + half * 16384u + wl;
#pragma unroll
      for (int L = 0; L < 2; L++)
        gload_lds16(A + aOff + (size_t)(half * 128 + L * 64) * K + k0,
                    smem + base + L * 8192);
    }
  };

  // prologue: halves 0..5 (kt0 full + kt1 B)
  for (int h = 0; h < 6; h++) stage(h);
  if constexpr (NSUB == 4) asm volatile("s_waitcnt vmcnt(4)" ::: "memory");
  else                     asm volatile("s_waitcnt vmcnt(2)" ::: "memory");
  __builtin_amdgcn_s_barrier();
  asm volatile("" ::: "memory");
  __builtin_amdgcn_sched_barrier(0);

  f32x4 acc[8][NSUB] = {};
  bf16x8 bfr[NSUB][2], bnx[2][2];

  // initial next-B (= kt0's B, buf0): safe — all waves passed vmcnt+barrier
#pragma unroll
  for (int n = 0; n < 2; n++) {
    const int r = wc * (16*NSUB) + n * 16 + l16;
#pragma unroll
    for (int ks = 0; ks < 2; ks++) {
      const int cb = ks * 64 + lhi * 16;
      bnx[n][ks] = *(const bf16x8*)(smem + 65536u + r * 128 + (cb ^ ((r & 7) << 4)));
    }
  }

  for (int kt = 0; kt < NKT; kt++) {
    const int cur = kt & 1;
    const uint32_t aB = cur * 32768u;
    const uint32_t bB = 65536u + cur * (8192u*NSUB);
#pragma unroll
    for (int p = 0; p < 4; p++) {
      if (p == 0) {
#pragma unroll
        for (int n = 0; n < 2; n++)
#pragma unroll
          for (int ks = 0; ks < 2; ks++) bfr[n][ks] = bnx[n][ks];
        if constexpr (NSUB == 4) {
#pragma unroll
          for (int n = 2; n < 4; n++) {
            const int r = wc * (16*NSUB) + n * 16 + l16;
#pragma unroll
            for (int ks = 0; ks < 2; ks++) {
              const int cb = ks * 64 + lhi * 16;
              bfr[n][ks] = *(const bf16x8*)(smem + bB + r * 128 + (cb ^ ((r & 7) << 4)));
            }
          }
        }
      }
      bf16x8 afr[2][2];
#pragma unroll
      for (int mm = 0; mm < 2; mm++) {
        const int r = wr * 128 + p * 32 + mm * 16 + l16;
#pragma unroll
        for (int ks = 0; ks < 2; ks++) {
          const int cb = ks * 64 + lhi * 16;
          afr[mm][ks] = *(const bf16x8*)(smem + aB + r * 128 + (cb ^ ((r & 7) << 4)));
        }
      }
      const int h = 4 * kt + p + 6;
      if (h < 4 * NKT) stage(h);
      __builtin_amdgcn_s_barrier();
      asm volatile("s_waitcnt lgkmcnt(0)" ::: "memory");
      __builtin_amdgcn_sched_barrier(0);
      __builtin_amdgcn_s_setprio(1);
#pragma unroll
      for (int mm = 0; mm < 2; mm++)
#pragma unroll
        for (int n = 0; n < NSUB; n++)
#pragma unroll
          for (int ks = 0; ks < 2; ks++)
            acc[2 * p + mm][n] = __builtin_amdgcn_mfma_f32_16x16x32_bf16(
                afr[mm][ks], bfr[n][ks], acc[2 * p + mm][n], 0, 0, 0);
      __builtin_amdgcn_s_setprio(0);
      if (p == 2) {
        // next-tile B landed after this wait (+ end barrier -> all waves)
        if constexpr (NSUB == 4) asm volatile("s_waitcnt vmcnt(6)" ::: "memory");
        else                     asm volatile("s_waitcnt vmcnt(5)" ::: "memory");
      }
      if (p == 3) {
        if (kt < NKT - 2) {
          if constexpr (NSUB == 4) asm volatile("s_waitcnt vmcnt(4)" ::: "memory");
          else                     asm volatile("s_waitcnt vmcnt(2)" ::: "memory");
        } else if (kt == NKT - 2) {
          asm volatile("s_waitcnt vmcnt(0)" ::: "memory");
        }
        if (kt + 1 < NKT) {      // register-prefetch next tile's B frags
          const uint32_t bN = 65536u + ((kt + 1) & 1) * (8192u*NSUB);
#pragma unroll
          for (int n = 0; n < 2; n++) {
            const int r = wc * (16*NSUB) + n * 16 + l16;
#pragma unroll
            for (int ks = 0; ks < 2; ks++) {
              const int cb = ks * 64 + lhi * 16;
              bnx[n][ks] = *(const bf16x8*)(smem + bN + r * 128 + (cb ^ ((r & 7) << 4)));
            }
          }
        }
      }
      __builtin_amdgcn_s_barrier();
      asm volatile("" ::: "memory");
      __builtin_amdgcn_sched_barrier(0);
    }
  }

#pragma unroll
  for (int m = 0; m < 8; m++) {
    const int rbase = rowT0 + wr * 128 + m * 16 + lhi * 4;
#pragma unroll
    for (int n = 0; n < NSUB; n++) {
      const int col = colT0 + wc * (16*NSUB) + n * 16 + l16;
      const float bv = bias[col];
#pragma unroll
      for (int j = 0; j < 4; j++) {
        float v = acc[m][n][j] + bv;
        if (OUT_BF16) ((bf16_t*)Cout)[(size_t)(rbase + j) * ldc + col] = __float2bfloat16(v);
        else          ((float*)Cout)[(size_t)(rbase + j) * ldc + col] = v;
      }
    }
  }
}

// ---------------- rotary (xPos) on q,k in-place; k scaled 1/sqrt(dqk) -------
__global__ void rotary_kernel(bf16_t* __restrict__ q, bf16_t* __restrict__ k,
                              const int* __restrict__ startp) {
  int t = blockIdx.x * 256 + threadIdx.x;
  if (t >= B_*N_*H_*16) return;
  int dg = t & 15;
  int rest = t >> 4;                          // (b*N+n)*H + h
  int n = (rest >> 4) & (N_ - 1);
  int h = rest & 15;
  float pos = (float)(startp[0] + n);
  size_t base = (size_t)(rest >> 4) * QKVG_LD + h * 128 + dg * 8;
  bf16x8 qv = *(const bf16x8*)(q + base);
  bf16x8 kv = *(const bf16x8*)(k + base);
  bf16x8 qo, ko;
  const float KS = 0.08838834764831843f;
#pragma unroll
  for (int p = 0; p < 4; p++) {
    int j = dg * 4 + p;
    float theta = exp2f(-13.287712379549449f * ((float)j * (1.0f/63.0f)));
    float ang = pos * theta;
    float s, c;
    sincosf(ang, &s, &c);
    float qa = (float)qv[2*p], qb = (float)qv[2*p+1];
    float ka = (float)kv[2*p], kb = (float)kv[2*p+1];
    qo[2*p]   = (__bf16)(qa*c - qb*s);
    qo[2*p+1] = (__bf16)(qb*c + qa*s);
    ko[2*p]   = (__bf16)((ka*c - kb*s) * KS);
    ko[2*p+1] = (__bf16)((kb*c + ka*s) * KS);
  }
  *(bf16x8*)(q + base) = qo;
  *(bf16x8*)(k + base) = ko;
}

// ---------------- per-chunk KV^T = V^T . K'  (parallel over b,h,chunk) ------
__global__ __launch_bounds__(256)
void chunk_kvt_kernel(const bf16_t* __restrict__ kb, const bf16_t* __restrict__ vb,
                      bf16_t* __restrict__ kvt) {
  __shared__ alignas(16) char lds[32768];
  char* vts = lds;
  char* kts = lds + 16384;

  const int tid = threadIdx.x, wave = tid >> 6, lane = tid & 63;
  const int l16 = lane & 15, lhi = lane >> 4;
  const int blk = blockIdx.x;              // bh*NC + ch
  const int bh = blk >> 5, ch = blk & 31;
  const int h = bh & (H_ - 1);
  const float log2g = head_log2g(h);
  const int n0 = ch * 64;

  const size_t bhbase = (size_t)(bh >> 4) * N_ * QKVG_LD + (size_t)h * 128;

#pragma unroll
  for (int it = 0; it < 4; it++) {
    int j = it*16 + (tid >> 4);
    int e0 = (tid & 15) * 8;
    bf16x8 vv = *(const bf16x8*)(vb + bhbase + (size_t)(n0 + j)*QKVG_LD + e0);
    bf16x8 kk = *(const bf16x8*)(kb + bhbase + (size_t)(n0 + j)*QKVG_LD + e0);
    float kvd = exp2f((float)(63 - j) * log2g);
#pragma unroll
    for (int m = 0; m < 8; m++) {
      int e = e0 + m;
      *(__bf16*)(vts + e*128 + ((j*2) ^ ((e&7)<<4))) = vv[m];
      *(__bf16*)(kts + e*128 + ((j*2) ^ ((e&7)<<4))) = (__bf16)((float)kk[m] * kvd);
    }
  }
  __syncthreads();

  f32x4 acc[2][8] = {};
#pragma unroll
  for (int kk2 = 0; kk2 < 2; kk2++) {
#pragma unroll
    for (int et = 0; et < 2; et++) {
      int e = (2*wave + et)*16 + l16;
      bf16x8 vf = *(const bf16x8*)(vts + e*128 + (((kk2*32 + lhi*8)*2) ^ ((e&7)<<4)));
#pragma unroll
      for (int dt = 0; dt < 8; dt++) {
        int d = dt*16 + l16;
        bf16x8 kf = *(const bf16x8*)(kts + d*128 + (((kk2*32 + lhi*8)*2) ^ ((d&7)<<4)));
        acc[et][dt] = __builtin_amdgcn_mfma_f32_16x16x32_bf16(vf, kf, acc[et][dt], 0, 0, 0);
      }
    }
  }

  const size_t obase = (size_t)blk * 16384;
#pragma unroll
  for (int et = 0; et < 2; et++)
#pragma unroll
    for (int dt = 0; dt < 8; dt++)
#pragma unroll
      for (int j = 0; j < 4; j++) {
        int e = (2*wave + et)*16 + lhi*4 + j;
        int d = dt*16 + l16;
        kvt[obase + e*128 + d] = __float2bfloat16(acc[et][dt][j]);
      }
}

// ---------------- state scan over chunks (element-parallel) ----------------
__global__ __launch_bounds__(256)
void state_scan_kernel(const bf16_t* __restrict__ kvt, const float* __restrict__ prev,
                       bf16_t* __restrict__ sbft, float* __restrict__ out_state) {
  int p = blockIdx.x * 256 + threadIdx.x;     // over B*H*16384
  int bh = p >> 14;
  int ed = p & 16383;
  int e = ed >> 7, d = ed & 127;
  int h = bh & (H_ - 1);
  const float cdecay = exp2f(64.0f * head_log2g(h));

  float S = prev[(size_t)bh*16384 + d*128 + e];
  size_t boff = (size_t)bh * (NC_*16384) + ed;
  for (int ch = 0; ch < NC_; ch++) {
    sbft[boff] = __float2bfloat16(S);
    S = S * cdecay + __bfloat162float(kvt[boff]);
    boff += 16384;
  }
  out_state[(size_t)bh*16384 + d*128 + e] = S;
}

// ---------------- per-chunk output + fused GroupNorm*SiLU(gate) -------------
// o = (q k^T ∘ D) @ v + (q @ S_entry) * cross_decay; then per-row (128-wide)
// groupnorm, multiply by silu(gate), write bf16 `gated` [M,2048].
__global__ __launch_bounds__(256)
void chunk_out_kernel(const bf16_t* __restrict__ qb, const bf16_t* __restrict__ kb,
                      const bf16_t* __restrict__ vb, const bf16_t* __restrict__ gb,
                      const bf16_t* __restrict__ sbft, bf16_t* __restrict__ gated) {
  __shared__ alignas(16) char lds[32768];
  char* vts = lds;                 // V^T 16KB   (phase 1)
  char* ats = lds + 16384;         // att 8KB    (phase 1)
  float* o_lds = (float*)lds;      // 64x128 f32 (phase 2, after barrier)

  const int tid = threadIdx.x, wave = tid >> 6, lane = tid & 63;
  const int l16 = lane & 15, lhi = lane >> 4;
  const int blk = blockIdx.x;              // bh*NC + ch
  const int bh = blk >> 5, ch = blk & 31;
  const int h = bh & (H_ - 1);
  const int b = bh >> 4;
  const float log2g = head_log2g(h);
  const int n0 = ch * 64;

  const size_t bhbase = (size_t)b * N_ * QKVG_LD + (size_t)h * 128;
  const bf16_t* Srow = sbft + (size_t)blk * 16384;   // [e][d]

#pragma unroll
  for (int it = 0; it < 4; it++) {
    int j = it*16 + (tid >> 4);
    int e0 = (tid & 15) * 8;
    bf16x8 vv = *(const bf16x8*)(vb + bhbase + (size_t)(n0 + j)*QKVG_LD + e0);
#pragma unroll
    for (int m = 0; m < 8; m++) {
      int e = e0 + m;
      *(__bf16*)(vts + e*128 + ((j*2) ^ ((e&7)<<4))) = vv[m];
    }
  }

  bf16x8 qf[4];
#pragma unroll
  for (int dk = 0; dk < 4; dk++)
    qf[dk] = *(const bf16x8*)(qb + bhbase + (size_t)(n0 + wave*16 + l16)*QKVG_LD + dk*32 + lhi*8);

  f32x4 aacc[4] = {};
#pragma unroll
  for (int jt = 0; jt < 4; jt++) {
#pragma unroll
    for (int dk = 0; dk < 4; dk++) {
      bf16x8 kf = *(const bf16x8*)(kb + bhbase + (size_t)(n0 + jt*16 + l16)*QKVG_LD + dk*32 + lhi*8);
      aacc[jt] = __builtin_amdgcn_mfma_f32_16x16x32_bf16(qf[dk], kf, aacc[jt], 0, 0, 0);
    }
  }
#pragma unroll
  for (int jt = 0; jt < 4; jt++)
#pragma unroll
    for (int j = 0; j < 4; j++) {
      int i = wave*16 + lhi*4 + j;
      int jc = jt*16 + l16;
      aacc[jt][j] *= (i >= jc) ? exp2f((float)(i - jc) * log2g) : 0.0f;
    }

#pragma unroll
  for (int jt = 0; jt < 4; jt++)
#pragma unroll
    for (int j = 0; j < 4; j++) {
      int i = wave*16 + lhi*4 + j;
      int jc = jt*16 + l16;
      *(__bf16*)(ats + i*128 + ((jc*2) ^ ((i&7)<<4))) = (__bf16)aacc[jt][j];
    }
  __syncthreads();

  f32x4 oacc[8] = {};
#pragma unroll
  for (int et = 0; et < 8; et++) {
#pragma unroll
    for (int dk = 0; dk < 4; dk++) {
      int e = et*16 + l16;
      bf16x8 sf = *(const bf16x8*)(Srow + e*128 + dk*32 + lhi*8);
      oacc[et] = __builtin_amdgcn_mfma_f32_16x16x32_bf16(qf[dk], sf, oacc[et], 0, 0, 0);
    }
  }
#pragma unroll
  for (int j = 0; j < 4; j++) {
    int i = wave*16 + lhi*4 + j;
    float f = exp2f((float)(i + 1) * log2g);
#pragma unroll
    for (int et = 0; et < 8; et++) oacc[et][j] *= f;
  }

#pragma unroll
  for (int kk2 = 0; kk2 < 2; kk2++) {
    int i = wave*16 + l16;
    bf16x8 af = *(const bf16x8*)(ats + i*128 + (((kk2*32 + lhi*8)*2) ^ ((i&7)<<4)));
#pragma unroll
    for (int et = 0; et < 8; et++) {
      int e = et*16 + l16;
      bf16x8 vf = *(const bf16x8*)(vts + e*128 + (((kk2*32 + lhi*8)*2) ^ ((e&7)<<4)));
      oacc[et] = __builtin_amdgcn_mfma_f32_16x16x32_bf16(af, vf, oacc[et], 0, 0, 0);
    }
  }

  // ---- stage o rows in LDS (overwrites vts/ats after barrier) ----
  __syncthreads();
#pragma unroll
  for (int et = 0; et < 8; et++)
#pragma unroll
    for (int j = 0; j < 4; j++) {
      int i = wave*16 + lhi*4 + j;
      o_lds[i*128 + et*16 + l16] = oacc[et][j];
    }
  __syncthreads();

  // ---- groupnorm + silu(gate): wave handles rows wave*16 .. +15 ----
  for (int rr = 0; rr < 16; rr++) {
    int r = wave*16 + rr;
    float2 xv = *(const float2*)&o_lds[r*128 + lane*2];
    float s = xv.x + xv.y, ss = xv.x*xv.x + xv.y*xv.y;
#pragma unroll
    for (int off = 1; off < 64; off <<= 1) {
      s  += __shfl_xor(s, off);
      ss += __shfl_xor(ss, off);
    }
    float mu  = s * (1.0f/128.0f);
    float inv = rsqrtf(ss * (1.0f/128.0f) - mu*mu + 1e-6f);
    size_t grow = (size_t)b * N_ + (n0 + r);
    unsigned int gg = *(const unsigned int*)(gb + grow*QKVG_LD + h*128 + lane*2);
    float g0 = bfu2f((unsigned short)(gg & 0xffff));
    float g1 = bfu2f((unsigned short)(gg >> 16));
    float r0 = (xv.x - mu) * inv * (g0 / (1.0f + expf(-g0)));
    float r1 = (xv.y - mu) * inv * (g1 / (1.0f + expf(-g1)));
    ushort2 o2; o2.x = f2bfu(r0); o2.y = f2bfu(r1);
    *(ushort2*)(gated + grow*2048 + h*128 + lane*2) = o2;
  }
}

// ---------------- launch ----------------
extern "C" void kernel_launch(void* const* d_in, const int* in_sizes, int n_in,
                              void* d_out, int out_size, void* d_ws, size_t ws_size,
                              hipStream_t stream) {
  const float* x    = (const float*)d_in[0];
  const float* prev = (const float*)d_in[1];
  const float* Wq = (const float*)d_in[2];  const float* bq = (const float*)d_in[3];
  const float* Wk = (const float*)d_in[4];  const float* bk = (const float*)d_in[5];
  const float* Wv = (const float*)d_in[6];  const float* bv = (const float*)d_in[7];
  const float* Wg = (const float*)d_in[8];  const float* bg = (const float*)d_in[9];
  const float* Wo = (const float*)d_in[10]; const float* bo = (const float*)d_in[11];
  const int* startp = (const int*)d_in[12];

  float* out = (float*)d_out;                               // B*N*E
  float* out_state = out + (size_t)B_*N_*E_;                // B*H*DQK*DV

  char* w = (char*)d_ws;
  const size_t XN = (size_t)B_*N_*E_;       // 8388608
  const size_t WN = (size_t)E_*E_;          // 4194304
  bf16_t* xb   = (bf16_t*)w;             w += XN*2;                  // 16MB (reused as gated)
  bf16_t* qkvg = (bf16_t*)w;             w += (size_t)M_*QKVG_LD*2;  // 64MB
  bf16_t* wob  = (bf16_t*)w;             w += WN*2;                  // 8MB
  char*   wcat_region = w;               w += 4*WN*2;                // 32MB
  bf16_t* wcat = (bf16_t*)wcat_region;
  bf16_t* sbft = (bf16_t*)w;             w += (size_t)B_*H_*NC_*16384*2; // 32MB
  bf16_t* kvt   = (bf16_t*)wcat_region;  // alias (wcat dead after QKVG GEMM)
  float*  bcat  = (float*)sbft;   // 32KB at sbft head; consumed before state_scan

  hipFuncSetAttribute(reinterpret_cast<const void*>(gemm8_kernel<true,4>),
                      hipFuncAttributeMaxDynamicSharedMemorySize, 131072);
  hipFuncSetAttribute(reinterpret_cast<const void*>(gemm8_kernel<false,2>),
                      hipFuncAttributeMaxDynamicSharedMemorySize, 98304);

  // all converts + bias concat in one launch
  cvt_all_kernel<<<28680, 256, 0, stream>>>(x, Wq, Wk, Wv, Wg, Wo, bq, bk, bv, bg,
                                            xb, wcat, wob, bcat);

  // fused QKVG projection: [4096,2048] @ [8192,2048]^T -> [4096,8192]
  gemm8_kernel<true,4><<<512, 512, 131072, stream>>>(xb, wcat, bcat, (void*)qkvg,
                                                     E_, QKVG_LD, 16);

  rotary_kernel<<<(B_*N_*H_*16)/256, 256, 0, stream>>>(qkvg, qkvg + 2048, startp);

  chunk_kvt_kernel<<<B_*H_*NC_, 256, 0, stream>>>(qkvg + 2048, qkvg + 4096, kvt);
  state_scan_kernel<<<(B_*H_*16384)/256, 256, 0, stream>>>(kvt, prev, sbft, out_state);
  chunk_out_kernel<<<B_*H_*NC_, 256, 0, stream>>>(qkvg, qkvg + 2048, qkvg + 4096,
                                                  qkvg + 6144, sbft, xb /*gated*/);

  // output projection: [4096,2048] @ [2048,2048]^T -> [4096,2048] f32, 256 blocks
  gemm8_kernel<false,2><<<256, 512, 98304, stream>>>(xb, wob, bo, (void*)out,
                                                     E_, E_, 16);
}